// Round 13
// baseline (427.802 us; speedup 1.0000x reference)
//
#include <hip/hip_runtime.h>
#include <stdint.h>

// Problem constants (B=256, L=2048, H=64, TE=64)
#define NB 256
#define NL 2048

typedef __attribute__((ext_vector_type(8))) short short8;
typedef __attribute__((ext_vector_type(4))) float f32x4;
#define MFMA16(a,b,c) __builtin_amdgcn_mfma_f32_16x16x32_bf16(a,b,c,0,0,0)

// ---------- bf16 helpers ----------
// R10: W-as-A operand swap caused replay-divergence — dead.
// R11: HW packed cvt (v_cvt_pk_bf16_f32) proven safe; R13: also used for
// single-value converts (pk with duplicated input, take low half) — 1 inst
// vs ~4-5 for the manual rounding sequence. RNE per element == f2bf.
static __device__ __forceinline__ unsigned short f2bf(float f) {
    union { float f; uint32_t u; } v; v.f = f;
    uint32_t u = v.u;
    uint32_t r = u + 0x7fffu + ((u >> 16) & 1u);
    return (unsigned short)(r >> 16);
}
static __device__ __forceinline__ float bflo(uint32_t u) {
    union { uint32_t u; float f; } v; v.u = u << 16; return v.f;
}
static __device__ __forceinline__ float bfhi(uint32_t u) {
    union { uint32_t u; float f; } v; v.u = u & 0xffff0000u; return v.f;
}
#if __has_builtin(__builtin_amdgcn_cvt_pk_bf16_f32)
typedef __attribute__((ext_vector_type(2))) __bf16 bf16x2_t;
static __device__ __forceinline__ uint32_t pk2(float lo, float hi) {
    union { bf16x2_t v; uint32_t u; } c;
    c.v = __builtin_amdgcn_cvt_pk_bf16_f32(lo, hi);
    return c.u;
}
static __device__ __forceinline__ unsigned short bf1(float v) {
    union { bf16x2_t v; uint32_t u; } c;
    c.v = __builtin_amdgcn_cvt_pk_bf16_f32(v, v);
    return (unsigned short)(c.u & 0xffffu);
}
#else
static __device__ __forceinline__ uint32_t pk2(float lo, float hi) {
    return ((uint32_t)f2bf(hi) << 16) | (uint32_t)f2bf(lo);
}
static __device__ __forceinline__ unsigned short bf1(float v) { return f2bf(v); }
#endif
static __device__ __forceinline__ short8 frag8(const float* p) {
    short8 r;
#pragma unroll
    for (int j = 0; j < 8; ++j) r[j] = (short)f2bf(p[j]);
    return r;
}

// =====================================================================
// kernel 1: MFMA prep — time-MLP + proj + gates -> packed (a,b)
// R12 structure (direct dwordx4 GEMM3 stores) + R13 bf1 epilogue diet.
// =====================================================================
__global__ __launch_bounds__(256, 3) void prep_kernel(
    const float* __restrict__ x, const float* __restrict__ t,
    const float* __restrict__ mtok,
    const float* __restrict__ te_w1, const float* __restrict__ te_b1,
    const float* __restrict__ te_w2, const float* __restrict__ te_b2,
    const float* __restrict__ fpw, const float* __restrict__ fpb,
    const float* __restrict__ bpw, const float* __restrict__ bpb,
    const float* __restrict__ fwz, const float* __restrict__ fbz,
    const float* __restrict__ fwh, const float* __restrict__ fbh,
    const float* __restrict__ bwz, const float* __restrict__ bbz,
    const float* __restrict__ bwh, const float* __restrict__ bbh,
    int b0,
    uint32_t* __restrict__ abf,              // [Bg*64, L] packed (a lo, b hi)
    uint32_t* __restrict__ abb)
{
    __shared__ __align__(16) unsigned short s_te1[64*72];     //  9216 B
    __shared__ __align__(16) unsigned short s_tenc[64*72];    //  9216 B
    __shared__ __align__(16) unsigned short s_xa[64*40];      //  5120 B
    __shared__ __align__(16) unsigned short s_inp[2][64*72];  // 18432 B

    const int tid = threadIdx.x;
    const int w   = tid >> 6;     // wave 0..3
    const int l   = tid & 63;
    const int lq  = l >> 4;       // quad
    const int ln  = l & 15;

    short8 bte[2];
    {
        const float* row = te_w2 + (w*16 + ln)*64;
#pragma unroll
        for (int ks = 0; ks < 2; ++ks) bte[ks] = frag8(row + lq*8 + ks*32);
    }
    short8 bpj[2][3];
#pragma unroll
    for (int p = 0; p < 2; ++p) {
        const int g = 2*w + p;
        const float* PW = (g < 4) ? fpw : bpw;
        const float* row = PW + ((g & 3)*16 + ln)*67;
#pragma unroll
        for (int ks = 0; ks < 2; ++ks) {
            float tmp[8];
#pragma unroll
            for (int j = 0; j < 8; ++j) tmp[j] = row[3 + lq*8 + ks*32 + j];
            bpj[p][ks] = frag8(tmp);
        }
        {
            float tmp[8];
#pragma unroll
            for (int j = 0; j < 8; ++j) tmp[j] = (lq == 0 && j < 3) ? row[j] : 0.f;
            bpj[p][2] = frag8(tmp);
        }
    }
    const int wdir = w >> 1, wnp = w & 1;
    short8 bgz[2][2], bgh[2][2];
    float bias_gz[2], bias_gh[2];
    {
        const float* WZ = wdir ? bwz : fwz;
        const float* WH = wdir ? bwh : fwh;
        const float* BZ = wdir ? bbz : fbz;
        const float* BH = wdir ? bbh : fbh;
#pragma unroll
        for (int nt2 = 0; nt2 < 2; ++nt2) {
            const int nt = wnp*2 + nt2;
            const float* rz = WZ + (nt*16 + ln)*64;
            const float* rh = WH + (nt*16 + ln)*64;
#pragma unroll
            for (int ks = 0; ks < 2; ++ks) {
                bgz[nt2][ks] = frag8(rz + lq*8 + ks*32);
                bgh[nt2][ks] = frag8(rh + lq*8 + ks*32);
            }
            bias_gz[nt2] = BZ[nt*16 + ln];
            bias_gh[nt2] = BH[nt*16 + ln];
        }
    }
    const float bias_te = te_b2[w*16 + ln];
    float bias_pj[2];
#pragma unroll
    for (int p = 0; p < 2; ++p) {
        const int g = 2*w + p;
        bias_pj[p] = ((g < 4) ? fpb : bpb)[(g & 3)*16 + ln];
    }
    const float mt0 = mtok[0], mt1 = mtok[1];

    const int baseposl = blockIdx.x * 256;

#pragma unroll 1
    for (int ch = 0; ch < 4; ++ch) {
        const int chbase = baseposl + ch*64;
        const int ll0   = chbase & 2047;
        const int bl    = chbase >> 11;
        const int gbase = (b0 << 11) + chbase;

        __syncthreads();   // phase0 writes vs prior chunk's reads

        // ---- phase 0: stage te1 + xa ----
        {
            const int pos = tid & 63;
            const float tv = t[gbase + pos];
            const int k0 = (tid >> 6) * 16;
            uint32_t* dst = (uint32_t*)(s_te1 + pos*72 + k0);
#pragma unroll
            for (int kk = 0; kk < 16; kk += 2) {
                float v0 = fmaxf(fmaf(tv, te_w1[k0+kk],   te_b1[k0+kk]),   0.f);
                float v1 = fmaxf(fmaf(tv, te_w1[k0+kk+1], te_b1[k0+kk+1]), 0.f);
                dst[kk >> 1] = pk2(v0, v1);
            }
#pragma unroll
            for (int i = tid; i < 64*20; i += 256) {
                if ((i % 20) >= 2) ((uint32_t*)s_xa)[i] = 0;
            }
            if (tid < 64) {
                const float* xp = x + (size_t)(gbase + tid)*3;
                const float mc = xp[2];
                const float x0 = (mc == 0.f) ? mt0 : xp[0];
                const float x1 = (mc == 0.f) ? mt1 : xp[1];
                uint32_t* xr = (uint32_t*)(s_xa + tid*40);
                xr[0] = pk2(x0, x1);
                xr[1] = pk2(mc, 0.f);
            }
        }
        __syncthreads();

        // ---- GEMM1: tenc = te1 * te_w2^T + b ----
        {
            const int o = w*16 + ln;
#pragma unroll
            for (int mt = 0; mt < 4; ++mt) {
                f32x4 c = {0.f, 0.f, 0.f, 0.f};
#pragma unroll
                for (int ks = 0; ks < 2; ++ks) {
                    const short8 a = *(const short8*)(s_te1 + (mt*16+ln)*72 + lq*8 + ks*32);
                    c = MFMA16(a, bte[ks], c);
                }
#pragma unroll
                for (int r = 0; r < 4; ++r) {
                    const int m = mt*16 + lq*4 + r;
                    s_tenc[m*72 + o] = bf1(c[r] + bias_te);
                }
            }
        }
        __syncthreads();

        // ---- GEMM2: inp_{f,b} = [tenc | x3pad] * pw'^T + pb ----
        {
#pragma unroll
            for (int mt = 0; mt < 4; ++mt) {
                short8 a0 = *(const short8*)(s_tenc + (mt*16+ln)*72 + lq*8);
                short8 a1 = *(const short8*)(s_tenc + (mt*16+ln)*72 + lq*8 + 32);
                short8 a2 = *(const short8*)(s_xa   + (mt*16+ln)*40 + lq*8);
#pragma unroll
                for (int p = 0; p < 2; ++p) {
                    const int g = 2*w + p;
                    const int dir = g >> 2;
                    const int o = (g & 3)*16 + ln;
                    f32x4 c = {0.f, 0.f, 0.f, 0.f};
                    c = MFMA16(a0, bpj[p][0], c);
                    c = MFMA16(a1, bpj[p][1], c);
                    c = MFMA16(a2, bpj[p][2], c);
#pragma unroll
                    for (int r = 0; r < 4; ++r) {
                        const int m = mt*16 + lq*4 + r;
                        s_inp[dir][m*72 + o] = bf1(c[r] + bias_pj[p]);
                    }
                }
            }
        }
        __syncthreads();

        // ---- GEMM3 fused: z + h-tilde -> (a,b) packed, direct dwordx4 stores ----
        {
            uint32_t* abD = (wdir ? abb : abf) + (size_t)(bl*64)*NL + ll0;
#pragma unroll
            for (int mt = 0; mt < 4; ++mt) {
                const short8 a0 = *(const short8*)(s_inp[wdir] + (mt*16+ln)*72 + lq*8);
                const short8 a1 = *(const short8*)(s_inp[wdir] + (mt*16+ln)*72 + lq*8 + 32);
#pragma unroll
                for (int nt2 = 0; nt2 < 2; ++nt2) {
                    f32x4 cz = {0.f, 0.f, 0.f, 0.f};
                    f32x4 ch2 = {0.f, 0.f, 0.f, 0.f};
                    cz  = MFMA16(a0, bgz[nt2][0], cz);
                    cz  = MFMA16(a1, bgz[nt2][1], cz);
                    ch2 = MFMA16(a0, bgh[nt2][0], ch2);
                    ch2 = MFMA16(a1, bgh[nt2][1], ch2);
                    const int o = (wnp*2 + nt2)*16 + ln;
                    uint4 v;
                    uint32_t* vp = (uint32_t*)&v;
#pragma unroll
                    for (int r = 0; r < 4; ++r) {
                        const float az = cz[r]  + bias_gz[nt2];
                        const float ah = ch2[r] + bias_gh[nt2];
                        const float z  = __builtin_amdgcn_rcpf(1.f + __expf(-az));
                        const float cc = fminf(fmaxf(ah, -15.f), 15.f);
                        const float e2 = __expf(2.f * cc);
                        const float th = 1.f - 2.f * __builtin_amdgcn_rcpf(e2 + 1.f);
                        vp[r] = pk2(1.f - z, z * th);
                    }
                    *(uint4*)(abD + (size_t)o*NL + mt*16 + lq*4) = v;
                }
            }
        }
    }
}

// =====================================================================
// kernel 2: chunk-parallel scan, h-split x2 (R9 structure + bf1 stores)
// =====================================================================
#define SSTR 129

__global__ __launch_bounds__(256) void scan3_kernel(
    const uint32_t* __restrict__ abf, const uint32_t* __restrict__ abb,
    unsigned short* __restrict__ hf, unsigned short* __restrict__ hb)
{
    __shared__ uint32_t s_seg[32*SSTR];
    __shared__ float s_A[8][33], s_B[8][33], s_Hin[8][33];
    __shared__ float s_H[32];

    const int rl  = blockIdx.x >> 2;
    const int dir = (blockIdx.x >> 1) & 1;
    const int h0  = (blockIdx.x & 1) * 32;
    const int tid = threadIdx.x;
    const int h   = tid & 31;
    const int q   = tid >> 5;

    const uint32_t* ab = (dir ? abb : abf) + (size_t)rl * 64 * NL + (size_t)h0 * NL;
    unsigned short* out = (dir ? hb : hf) + (size_t)rl * NL * 64 + h0;

    if (tid < 32) s_H[tid] = 0.f;
    __syncthreads();

#pragma unroll 1
    for (int si = 0; si < 16; ++si) {
        const int s  = dir ? (15 - si) : si;
        const int l0 = s * 128;

#pragma unroll
        for (int rep = 0; rep < 16; ++rep) {
            const int idx = rep*256 + tid;
            const int hh = idx >> 7, xx = idx & 127;
            s_seg[hh*SSTR + xx] = ab[(size_t)hh*NL + l0 + xx];
        }
        __syncthreads();

        uint32_t regs[16];
        float A = 1.f, Bc = 0.f;
#pragma unroll
        for (int i = 0; i < 16; ++i) {
            const int g = q*16 + i;
            const int xx = dir ? (127 - g) : g;
            const uint32_t uab = s_seg[h*SSTR + xx];
            regs[i] = uab;
            Bc = fmaf(bflo(uab), Bc, bfhi(uab));
            A *= bflo(uab);
        }
        s_A[q][h] = A; s_B[q][h] = Bc;
        __syncthreads();

        if (tid < 32) {
            float H = s_H[tid];
#pragma unroll
            for (int qq = 0; qq < 8; ++qq) {
                s_Hin[qq][tid] = H;
                H = fmaf(s_A[qq][tid], H, s_B[qq][tid]);
            }
            s_H[tid] = H;
        }
        __syncthreads();

        float hv = s_Hin[q][h];
#pragma unroll
        for (int i = 0; i < 16; ++i) {
            const int g = q*16 + i;
            const int xx = dir ? (127 - g) : g;
            const uint32_t uab = regs[i];
            out[(size_t)(l0 + xx)*64 + h] = bf1(hv);
            hv = fmaf(bflo(uab), hv, bfhi(uab));
        }
        __syncthreads();
    }
}

// =====================================================================
// kernel 3: MFMA head — recompute tenc, GEMM1 + shuffle-reduce
// =====================================================================
__global__ __launch_bounds__(256, 3) void head_kernel(
    const float* __restrict__ x, const float* __restrict__ t,
    const float* __restrict__ te_w1, const float* __restrict__ te_b1,
    const float* __restrict__ te_w2, const float* __restrict__ te_b2,
    const unsigned short* __restrict__ hf, const unsigned short* __restrict__ hb,
    const float* __restrict__ w1, const float* __restrict__ b1,
    const float* __restrict__ w2, const float* __restrict__ b2,
    int b0,
    float* __restrict__ out)
{
    __shared__ __align__(16) unsigned short s_a[64*200];
    __shared__ __align__(16) unsigned short s_te1[64*72];
    __shared__ float s_part[4][64];

    const int tid = threadIdx.x;
    const int w   = tid >> 6;
    const int l   = tid & 63;
    const int lq  = l >> 4;
    const int ln  = l & 15;

    short8 bw1[2][6];
    float b1v[2], w2v[2];
#pragma unroll
    for (int p = 0; p < 2; ++p) {
        const int o = (2*w + p)*16 + ln;
        const float* row = w1 + o*192;
#pragma unroll
        for (int ks = 0; ks < 6; ++ks) bw1[p][ks] = frag8(row + lq*8 + ks*32);
        b1v[p] = b1[o];
        w2v[p] = w2[o];
    }
    short8 bte[2];
    {
        const float* row = te_w2 + (w*16 + ln)*64;
#pragma unroll
        for (int ks = 0; ks < 2; ++ks) bte[ks] = frag8(row + lq*8 + ks*32);
    }
    const float bias_te = te_b2[w*16 + ln];
    const float bias2 = b2[0];

    const int baseposl = blockIdx.x * 256;

#pragma unroll 1
    for (int ch = 0; ch < 4; ++ch) {
        const int chbase = baseposl + ch*64;
        const int ll0   = chbase & 2047;
        const int bl    = chbase >> 11;
        const int gbase = (b0 << 11) + chbase;
        const size_t rowbase = (size_t)bl * NL * 64;

        {
#pragma unroll 1
            for (int seg = 0; seg < 2; ++seg) {
#pragma unroll
                for (int rep = 0; rep < 8; ++rep) {
                    const int idx = rep*256 + tid;
                    const int row = idx >> 5, c = idx & 31;
                    const float mc = x[(size_t)(gbase + row)*3 + 2];
                    const bool unm = mc > 0.f;
                    const uint32_t* src = (seg == 0)
                        ? (const uint32_t*)(hf + rowbase + (size_t)(unm ? (ll0+row) : (NL-1))*64)
                        : (const uint32_t*)(hb + rowbase + (size_t)(unm ? (ll0+row) : 0)*64);
                    ((uint32_t*)s_a)[row*100 + seg*32 + c] = src[c];
                }
            }
            const int pos = tid & 63;
            const float tv = t[gbase + pos];
            const int k0 = (tid >> 6) * 16;
            uint32_t* dst = (uint32_t*)(s_te1 + pos*72 + k0);
#pragma unroll
            for (int kk = 0; kk < 16; kk += 2) {
                float v0 = fmaxf(fmaf(tv, te_w1[k0+kk],   te_b1[k0+kk]),   0.f);
                float v1 = fmaxf(fmaf(tv, te_w1[k0+kk+1], te_b1[k0+kk+1]), 0.f);
                dst[kk >> 1] = pk2(v0, v1);
            }
        }
        __syncthreads();

        // ---- tenc GEMM -> s_a cols 128..191 ----
        {
            const int o = w*16 + ln;
#pragma unroll
            for (int mt = 0; mt < 4; ++mt) {
                f32x4 c = {0.f, 0.f, 0.f, 0.f};
#pragma unroll
                for (int ks = 0; ks < 2; ++ks) {
                    const short8 a = *(const short8*)(s_te1 + (mt*16+ln)*72 + lq*8 + ks*32);
                    c = MFMA16(a, bte[ks], c);
                }
#pragma unroll
                for (int r = 0; r < 4; ++r) {
                    const int m = mt*16 + lq*4 + r;
                    s_a[m*200 + 128 + o] = bf1(c[r] + bias_te);
                }
            }
        }
        __syncthreads();

        // ---- GEMM1 + in-register relu*w2 + quad shuffle-reduce ----
        {
#pragma unroll
            for (int mt = 0; mt < 4; ++mt) {
                short8 af[6];
#pragma unroll
                for (int ks = 0; ks < 6; ++ks)
                    af[ks] = *(const short8*)(s_a + (mt*16+ln)*200 + lq*8 + ks*32);
                float vs[4] = {0.f, 0.f, 0.f, 0.f};
#pragma unroll
                for (int p = 0; p < 2; ++p) {
                    f32x4 c = {0.f, 0.f, 0.f, 0.f};
#pragma unroll
                    for (int ks = 0; ks < 6; ++ks) c = MFMA16(af[ks], bw1[p][ks], c);
#pragma unroll
                    for (int r = 0; r < 4; ++r)
                        vs[r] += fmaxf(c[r] + b1v[p], 0.f) * w2v[p];
                }
#pragma unroll
                for (int mask = 1; mask < 16; mask <<= 1) {
#pragma unroll
                    for (int r = 0; r < 4; ++r)
                        vs[r] += __shfl_xor(vs[r], mask);
                }
                if (ln == 0) {
#pragma unroll
                    for (int r = 0; r < 4; ++r)
                        s_part[w][mt*16 + lq*4 + r] = vs[r];
                }
            }
        }
        __syncthreads();

        if (tid < 64) {
            out[gbase + tid] = s_part[0][tid] + s_part[1][tid]
                             + s_part[2][tid] + s_part[3][tid] + bias2;
        }
        __syncthreads();
    }
}

extern "C" void kernel_launch(void* const* d_in, const int* in_sizes, int n_in,
                              void* d_out, int out_size, void* d_ws, size_t ws_size,
                              hipStream_t stream)
{
    const float* x     = (const float*)d_in[0];
    const float* t     = (const float*)d_in[1];
    const float* mtok  = (const float*)d_in[2];
    const float* te_w1 = (const float*)d_in[3];
    const float* te_b1 = (const float*)d_in[4];
    const float* te_w2 = (const float*)d_in[5];
    const float* te_b2 = (const float*)d_in[6];
    const float* fpw   = (const float*)d_in[7];
    const float* fpb   = (const float*)d_in[8];
    const float* bpw   = (const float*)d_in[9];
    const float* bpb   = (const float*)d_in[10];
    const float* fwz   = (const float*)d_in[11];
    const float* fbz   = (const float*)d_in[12];
    const float* fwh   = (const float*)d_in[13];
    const float* fbh   = (const float*)d_in[14];
    const float* bwz   = (const float*)d_in[15];
    const float* bbz   = (const float*)d_in[16];
    const float* bwh   = (const float*)d_in[17];
    const float* bbh   = (const float*)d_in[18];
    const float* w1    = (const float*)d_in[19];
    const float* b1    = (const float*)d_in[20];
    const float* w2    = (const float*)d_in[21];
    const float* b2    = (const float*)d_in[22];

    const size_t per_b = 1572864ull;
    int Bg = NB;
    while ((size_t)Bg * per_b > ws_size && Bg > 1) Bg >>= 1;
    const int nG = NB / Bg;

    char* ws = (char*)d_ws;
    uint32_t*       abf  = (uint32_t*)(ws);
    uint32_t*       abb  = abf + (size_t)Bg * 64 * NL;
    unsigned short* hf   = (unsigned short*)(abb + (size_t)Bg * 64 * NL);
    unsigned short* hb   = hf + (size_t)Bg * NL * 64;

    for (int g = 0; g < nG; ++g) {
        const int b0 = g * Bg;

        prep_kernel<<<8 * Bg, 256, 0, stream>>>(
            x, t, mtok, te_w1, te_b1, te_w2, te_b2,
            fpw, fpb, bpw, bpb, fwz, fbz, fwh, fbh, bwz, bbz, bwh, bbh,
            b0, abf, abb);

        scan3_kernel<<<4 * Bg, 256, 0, stream>>>(abf, abb, hf, hb);

        head_kernel<<<8 * Bg, 256, 0, stream>>>(
            x, t, te_w1, te_b1, te_w2, te_b2,
            hf, hb, w1, b1, w2, b2, b0, (float*)d_out);
    }
}

// Round 14
// 372.867 us; speedup vs baseline: 1.1473x; 1.1473x over previous
//
#include <hip/hip_runtime.h>
#include <stdint.h>

// Problem constants (B=256, L=2048, H=64, TE=64)
#define NB 256
#define NL 2048

typedef __attribute__((ext_vector_type(8))) short short8;
typedef __attribute__((ext_vector_type(4))) float f32x4;
#define MFMA16(a,b,c) __builtin_amdgcn_mfma_f32_16x16x32_bf16(a,b,c,0,0,0)

// ---------- bf16 helpers ----------
// R10: W-as-A operand swap caused replay-divergence — dead.
// R11: HW packed cvt proven safe. R13: bf1 single-convert neutral (kept).
static __device__ __forceinline__ unsigned short f2bf(float f) {
    union { float f; uint32_t u; } v; v.f = f;
    uint32_t u = v.u;
    uint32_t r = u + 0x7fffu + ((u >> 16) & 1u);
    return (unsigned short)(r >> 16);
}
static __device__ __forceinline__ float bflo(uint32_t u) {
    union { uint32_t u; float f; } v; v.u = u << 16; return v.f;
}
static __device__ __forceinline__ float bfhi(uint32_t u) {
    union { uint32_t u; float f; } v; v.u = u & 0xffff0000u; return v.f;
}
#if __has_builtin(__builtin_amdgcn_cvt_pk_bf16_f32)
typedef __attribute__((ext_vector_type(2))) __bf16 bf16x2_t;
static __device__ __forceinline__ uint32_t pk2(float lo, float hi) {
    union { bf16x2_t v; uint32_t u; } c;
    c.v = __builtin_amdgcn_cvt_pk_bf16_f32(lo, hi);
    return c.u;
}
static __device__ __forceinline__ unsigned short bf1(float v) {
    union { bf16x2_t v; uint32_t u; } c;
    c.v = __builtin_amdgcn_cvt_pk_bf16_f32(v, v);
    return (unsigned short)(c.u & 0xffffu);
}
#else
static __device__ __forceinline__ uint32_t pk2(float lo, float hi) {
    return ((uint32_t)f2bf(hi) << 16) | (uint32_t)f2bf(lo);
}
static __device__ __forceinline__ unsigned short bf1(float v) { return f2bf(v); }
#endif
static __device__ __forceinline__ short8 frag8(const float* p) {
    short8 r;
#pragma unroll
    for (int j = 0; j < 8; ++j) r[j] = (short)f2bf(p[j]);
    return r;
}

// =====================================================================
// kernel 1: MFMA prep — R14: software-pipelined phases.
// {G3(ch) + P0(ch+1)} share a phase (disjoint LDS: s_inp vs s_te1/s_xa)
// -> 3 barriers/chunk, staging VMEM hidden under GEMM3 MFMA+exp.
// =====================================================================
__global__ __launch_bounds__(256, 3) void prep_kernel(
    const float* __restrict__ x, const float* __restrict__ t,
    const float* __restrict__ mtok,
    const float* __restrict__ te_w1, const float* __restrict__ te_b1,
    const float* __restrict__ te_w2, const float* __restrict__ te_b2,
    const float* __restrict__ fpw, const float* __restrict__ fpb,
    const float* __restrict__ bpw, const float* __restrict__ bpb,
    const float* __restrict__ fwz, const float* __restrict__ fbz,
    const float* __restrict__ fwh, const float* __restrict__ fbh,
    const float* __restrict__ bwz, const float* __restrict__ bbz,
    const float* __restrict__ bwh, const float* __restrict__ bbh,
    int b0,
    uint32_t* __restrict__ abf,              // [Bg*64, L] packed (a lo, b hi)
    uint32_t* __restrict__ abb)
{
    __shared__ __align__(16) unsigned short s_te1[64*72];     //  9216 B
    __shared__ __align__(16) unsigned short s_tenc[64*72];    //  9216 B
    __shared__ __align__(16) unsigned short s_xa[64*40];      //  5120 B
    __shared__ __align__(16) unsigned short s_inp[2][64*72];  // 18432 B

    const int tid = threadIdx.x;
    const int w   = tid >> 6;     // wave 0..3
    const int l   = tid & 63;
    const int lq  = l >> 4;       // quad
    const int ln  = l & 15;

    short8 bte[2];
    {
        const float* row = te_w2 + (w*16 + ln)*64;
#pragma unroll
        for (int ks = 0; ks < 2; ++ks) bte[ks] = frag8(row + lq*8 + ks*32);
    }
    short8 bpj[2][3];
#pragma unroll
    for (int p = 0; p < 2; ++p) {
        const int g = 2*w + p;
        const float* PW = (g < 4) ? fpw : bpw;
        const float* row = PW + ((g & 3)*16 + ln)*67;
#pragma unroll
        for (int ks = 0; ks < 2; ++ks) {
            float tmp[8];
#pragma unroll
            for (int j = 0; j < 8; ++j) tmp[j] = row[3 + lq*8 + ks*32 + j];
            bpj[p][ks] = frag8(tmp);
        }
        {
            float tmp[8];
#pragma unroll
            for (int j = 0; j < 8; ++j) tmp[j] = (lq == 0 && j < 3) ? row[j] : 0.f;
            bpj[p][2] = frag8(tmp);
        }
    }
    const int wdir = w >> 1, wnp = w & 1;
    short8 bgz[2][2], bgh[2][2];
    float bias_gz[2], bias_gh[2];
    {
        const float* WZ = wdir ? bwz : fwz;
        const float* WH = wdir ? bwh : fwh;
        const float* BZ = wdir ? bbz : fbz;
        const float* BH = wdir ? bbh : fbh;
#pragma unroll
        for (int nt2 = 0; nt2 < 2; ++nt2) {
            const int nt = wnp*2 + nt2;
            const float* rz = WZ + (nt*16 + ln)*64;
            const float* rh = WH + (nt*16 + ln)*64;
#pragma unroll
            for (int ks = 0; ks < 2; ++ks) {
                bgz[nt2][ks] = frag8(rz + lq*8 + ks*32);
                bgh[nt2][ks] = frag8(rh + lq*8 + ks*32);
            }
            bias_gz[nt2] = BZ[nt*16 + ln];
            bias_gh[nt2] = BH[nt*16 + ln];
        }
    }
    const float bias_te = te_b2[w*16 + ln];
    float bias_pj[2];
#pragma unroll
    for (int p = 0; p < 2; ++p) {
        const int g = 2*w + p;
        bias_pj[p] = ((g < 4) ? fpb : bpb)[(g & 3)*16 + ln];
    }
    const float mt0 = mtok[0], mt1 = mtok[1];

    const int baseposl = blockIdx.x * 256;

    // ---- phase lambdas ----
    auto P0 = [&](int ch) {   // stage te1 + xa data dwords (zero pad is hoisted)
        const int gbase = (b0 << 11) + baseposl + ch*64;
        const int pos = tid & 63;
        const float tv = t[gbase + pos];
        const int k0 = (tid >> 6) * 16;
        uint32_t* dst = (uint32_t*)(s_te1 + pos*72 + k0);
#pragma unroll
        for (int kk = 0; kk < 16; kk += 2) {
            float v0 = fmaxf(fmaf(tv, te_w1[k0+kk],   te_b1[k0+kk]),   0.f);
            float v1 = fmaxf(fmaf(tv, te_w1[k0+kk+1], te_b1[k0+kk+1]), 0.f);
            dst[kk >> 1] = pk2(v0, v1);
        }
        if (tid < 64) {
            const float* xp = x + (size_t)(gbase + tid)*3;
            const float mc = xp[2];
            const float x0 = (mc == 0.f) ? mt0 : xp[0];
            const float x1 = (mc == 0.f) ? mt1 : xp[1];
            uint32_t* xr = (uint32_t*)(s_xa + tid*40);
            xr[0] = pk2(x0, x1);
            xr[1] = pk2(mc, 0.f);
        }
    };
    auto G1 = [&]() {         // tenc = te1 * te_w2^T + b
        const int o = w*16 + ln;
#pragma unroll
        for (int mt = 0; mt < 4; ++mt) {
            f32x4 c = {0.f, 0.f, 0.f, 0.f};
#pragma unroll
            for (int ks = 0; ks < 2; ++ks) {
                const short8 a = *(const short8*)(s_te1 + (mt*16+ln)*72 + lq*8 + ks*32);
                c = MFMA16(a, bte[ks], c);
            }
#pragma unroll
            for (int r = 0; r < 4; ++r) {
                const int m = mt*16 + lq*4 + r;
                s_tenc[m*72 + o] = bf1(c[r] + bias_te);
            }
        }
    };
    auto G2 = [&]() {         // inp_{f,b} = [tenc | x3pad] * pw'^T + pb
#pragma unroll
        for (int mt = 0; mt < 4; ++mt) {
            short8 a0 = *(const short8*)(s_tenc + (mt*16+ln)*72 + lq*8);
            short8 a1 = *(const short8*)(s_tenc + (mt*16+ln)*72 + lq*8 + 32);
            short8 a2 = *(const short8*)(s_xa   + (mt*16+ln)*40 + lq*8);
#pragma unroll
            for (int p = 0; p < 2; ++p) {
                const int g = 2*w + p;
                const int dir = g >> 2;
                const int o = (g & 3)*16 + ln;
                f32x4 c = {0.f, 0.f, 0.f, 0.f};
                c = MFMA16(a0, bpj[p][0], c);
                c = MFMA16(a1, bpj[p][1], c);
                c = MFMA16(a2, bpj[p][2], c);
#pragma unroll
                for (int r = 0; r < 4; ++r) {
                    const int m = mt*16 + lq*4 + r;
                    s_inp[dir][m*72 + o] = bf1(c[r] + bias_pj[p]);
                }
            }
        }
    };
    auto G3 = [&](int ch) {   // gates -> (a,b), direct dwordx4 global stores
        const int chbase = baseposl + ch*64;
        const int ll0 = chbase & 2047;
        const int bl  = chbase >> 11;
        uint32_t* abD = (wdir ? abb : abf) + (size_t)(bl*64)*NL + ll0;
#pragma unroll
        for (int mt = 0; mt < 4; ++mt) {
            const short8 a0 = *(const short8*)(s_inp[wdir] + (mt*16+ln)*72 + lq*8);
            const short8 a1 = *(const short8*)(s_inp[wdir] + (mt*16+ln)*72 + lq*8 + 32);
#pragma unroll
            for (int nt2 = 0; nt2 < 2; ++nt2) {
                f32x4 cz = {0.f, 0.f, 0.f, 0.f};
                f32x4 ch2 = {0.f, 0.f, 0.f, 0.f};
                cz  = MFMA16(a0, bgz[nt2][0], cz);
                cz  = MFMA16(a1, bgz[nt2][1], cz);
                ch2 = MFMA16(a0, bgh[nt2][0], ch2);
                ch2 = MFMA16(a1, bgh[nt2][1], ch2);
                const int o = (wnp*2 + nt2)*16 + ln;
                uint4 v;
                uint32_t* vp = (uint32_t*)&v;
#pragma unroll
                for (int r = 0; r < 4; ++r) {
                    const float az = cz[r]  + bias_gz[nt2];
                    const float ah = ch2[r] + bias_gh[nt2];
                    const float z  = __builtin_amdgcn_rcpf(1.f + __expf(-az));
                    const float cc = fminf(fmaxf(ah, -15.f), 15.f);
                    const float e2 = __expf(2.f * cc);
                    const float th = 1.f - 2.f * __builtin_amdgcn_rcpf(e2 + 1.f);
                    vp[r] = pk2(1.f - z, z * th);
                }
                *(uint4*)(abD + (size_t)o*NL + mt*16 + lq*4) = v;
            }
        }
    };

    // xa zero pad: loop-invariant, fill once (dwords >= 2 of each 20-dword row)
#pragma unroll
    for (int i = tid; i < 64*20; i += 256) {
        if ((i % 20) >= 2) ((uint32_t*)s_xa)[i] = 0;
    }
    P0(0);
    __syncthreads();
    G1();
    __syncthreads();
    G2();
    __syncthreads();
#pragma unroll 1
    for (int ch = 0; ch < 4; ++ch) {
        G3(ch);                       // reads s_inp, writes global
        if (ch < 3) P0(ch + 1);       // writes s_te1/s_xa — disjoint, overlapped
        __syncthreads();
        if (ch < 3) {
            G1();
            __syncthreads();
            G2();
            __syncthreads();
        }
    }
}

// =====================================================================
// kernel 2: chunk-parallel scan, h-split x2 (unchanged from R13)
// =====================================================================
#define SSTR 129

__global__ __launch_bounds__(256) void scan3_kernel(
    const uint32_t* __restrict__ abf, const uint32_t* __restrict__ abb,
    unsigned short* __restrict__ hf, unsigned short* __restrict__ hb)
{
    __shared__ uint32_t s_seg[32*SSTR];
    __shared__ float s_A[8][33], s_B[8][33], s_Hin[8][33];
    __shared__ float s_H[32];

    const int rl  = blockIdx.x >> 2;
    const int dir = (blockIdx.x >> 1) & 1;
    const int h0  = (blockIdx.x & 1) * 32;
    const int tid = threadIdx.x;
    const int h   = tid & 31;
    const int q   = tid >> 5;

    const uint32_t* ab = (dir ? abb : abf) + (size_t)rl * 64 * NL + (size_t)h0 * NL;
    unsigned short* out = (dir ? hb : hf) + (size_t)rl * NL * 64 + h0;

    if (tid < 32) s_H[tid] = 0.f;
    __syncthreads();

#pragma unroll 1
    for (int si = 0; si < 16; ++si) {
        const int s  = dir ? (15 - si) : si;
        const int l0 = s * 128;

#pragma unroll
        for (int rep = 0; rep < 16; ++rep) {
            const int idx = rep*256 + tid;
            const int hh = idx >> 7, xx = idx & 127;
            s_seg[hh*SSTR + xx] = ab[(size_t)hh*NL + l0 + xx];
        }
        __syncthreads();

        uint32_t regs[16];
        float A = 1.f, Bc = 0.f;
#pragma unroll
        for (int i = 0; i < 16; ++i) {
            const int g = q*16 + i;
            const int xx = dir ? (127 - g) : g;
            const uint32_t uab = s_seg[h*SSTR + xx];
            regs[i] = uab;
            Bc = fmaf(bflo(uab), Bc, bfhi(uab));
            A *= bflo(uab);
        }
        s_A[q][h] = A; s_B[q][h] = Bc;
        __syncthreads();

        if (tid < 32) {
            float H = s_H[tid];
#pragma unroll
            for (int qq = 0; qq < 8; ++qq) {
                s_Hin[qq][tid] = H;
                H = fmaf(s_A[qq][tid], H, s_B[qq][tid]);
            }
            s_H[tid] = H;
        }
        __syncthreads();

        float hv = s_Hin[q][h];
#pragma unroll
        for (int i = 0; i < 16; ++i) {
            const int g = q*16 + i;
            const int xx = dir ? (127 - g) : g;
            const uint32_t uab = regs[i];
            out[(size_t)(l0 + xx)*64 + h] = bf1(hv);
            hv = fmaf(bflo(uab), hv, bfhi(uab));
        }
        __syncthreads();
    }
}

// =====================================================================
// kernel 3: MFMA head — R14: pipelined phases.
// B = {uint4 gather (s_a cols 0..127) + tenc GEMM (cols 128..191)} in one
// phase (VMEM hides under MFMA); mc cached in LDS; out-write folded into
// next chunk's A phase. 3 barriers/chunk.
// =====================================================================
__global__ __launch_bounds__(256, 3) void head_kernel(
    const float* __restrict__ x, const float* __restrict__ t,
    const float* __restrict__ te_w1, const float* __restrict__ te_b1,
    const float* __restrict__ te_w2, const float* __restrict__ te_b2,
    const unsigned short* __restrict__ hf, const unsigned short* __restrict__ hb,
    const float* __restrict__ w1, const float* __restrict__ b1,
    const float* __restrict__ w2, const float* __restrict__ b2,
    int b0,
    float* __restrict__ out)
{
    __shared__ __align__(16) unsigned short s_a[64*200];   // 25600 B
    __shared__ __align__(16) unsigned short s_te1[64*72];  //  9216 B
    __shared__ float s_part[4][64];                        //  1024 B
    __shared__ float s_mc[64];                             //   256 B

    const int tid = threadIdx.x;
    const int w   = tid >> 6;
    const int l   = tid & 63;
    const int lq  = l >> 4;
    const int ln  = l & 15;

    short8 bw1[2][6];
    float b1v[2], w2v[2];
#pragma unroll
    for (int p = 0; p < 2; ++p) {
        const int o = (2*w + p)*16 + ln;
        const float* row = w1 + o*192;
#pragma unroll
        for (int ks = 0; ks < 6; ++ks) bw1[p][ks] = frag8(row + lq*8 + ks*32);
        b1v[p] = b1[o];
        w2v[p] = w2[o];
    }
    short8 bte[2];
    {
        const float* row = te_w2 + (w*16 + ln)*64;
#pragma unroll
        for (int ks = 0; ks < 2; ++ks) bte[ks] = frag8(row + lq*8 + ks*32);
    }
    const float bias_te = te_b2[w*16 + ln];
    const float bias2 = b2[0];

    const int baseposl = blockIdx.x * 256;

    auto A = [&](int ch) {    // mc + te1 staging
        const int gbase = (b0 << 11) + baseposl + ch*64;
        if (tid < 64) s_mc[tid] = x[(size_t)(gbase + tid)*3 + 2];
        const int pos = tid & 63;
        const float tv = t[gbase + pos];
        const int k0 = (tid >> 6) * 16;
        uint32_t* dst = (uint32_t*)(s_te1 + pos*72 + k0);
#pragma unroll
        for (int kk = 0; kk < 16; kk += 2) {
            float v0 = fmaxf(fmaf(tv, te_w1[k0+kk],   te_b1[k0+kk]),   0.f);
            float v1 = fmaxf(fmaf(tv, te_w1[k0+kk+1], te_b1[k0+kk+1]), 0.f);
            dst[kk >> 1] = pk2(v0, v1);
        }
    };
    auto Bp = [&](int ch) {   // uint4 gather + tenc GEMM (disjoint s_a cols)
        const int chbase = baseposl + ch*64;
        const int ll0 = chbase & 2047;
        const int bl  = chbase >> 11;
        const size_t rowbase = (size_t)bl * NL * 64;
#pragma unroll
        for (int rep = 0; rep < 4; ++rep) {
            const int idx = rep*256 + tid;
            const int seg = idx >> 9;
            const int row = (idx >> 3) & 63;
            const int c   = idx & 7;
            const bool unm = s_mc[row] > 0.f;
            const uint4* src = (seg == 0)
                ? (const uint4*)(hf + rowbase + (size_t)(unm ? (ll0+row) : (NL-1))*64)
                : (const uint4*)(hb + rowbase + (size_t)(unm ? (ll0+row) : 0)*64);
            ((uint4*)s_a)[row*25 + seg*8 + c] = src[c];
        }
        const int o = w*16 + ln;
#pragma unroll
        for (int mt = 0; mt < 4; ++mt) {
            f32x4 c = {0.f, 0.f, 0.f, 0.f};
#pragma unroll
            for (int ks = 0; ks < 2; ++ks) {
                const short8 a = *(const short8*)(s_te1 + (mt*16+ln)*72 + lq*8 + ks*32);
                c = MFMA16(a, bte[ks], c);
            }
#pragma unroll
            for (int r = 0; r < 4; ++r) {
                const int m = mt*16 + lq*4 + r;
                s_a[m*200 + 128 + o] = bf1(c[r] + bias_te);
            }
        }
    };
    auto Cp = [&]() {         // GEMM1 + relu*w2 + quad shuffle-reduce
#pragma unroll
        for (int mt = 0; mt < 4; ++mt) {
            short8 af[6];
#pragma unroll
            for (int ks = 0; ks < 6; ++ks)
                af[ks] = *(const short8*)(s_a + (mt*16+ln)*200 + lq*8 + ks*32);
            float vs[4] = {0.f, 0.f, 0.f, 0.f};
#pragma unroll
            for (int p = 0; p < 2; ++p) {
                f32x4 c = {0.f, 0.f, 0.f, 0.f};
#pragma unroll
                for (int ks = 0; ks < 6; ++ks) c = MFMA16(af[ks], bw1[p][ks], c);
#pragma unroll
                for (int r = 0; r < 4; ++r)
                    vs[r] += fmaxf(c[r] + b1v[p], 0.f) * w2v[p];
            }
#pragma unroll
            for (int mask = 1; mask < 16; mask <<= 1) {
#pragma unroll
                for (int r = 0; r < 4; ++r)
                    vs[r] += __shfl_xor(vs[r], mask);
            }
            if (ln == 0) {
#pragma unroll
                for (int r = 0; r < 4; ++r)
                    s_part[w][mt*16 + lq*4 + r] = vs[r];
            }
        }
    };
    auto Dp = [&](int ch) {   // out write
        const int gbase = (b0 << 11) + baseposl + ch*64;
        if (tid < 64) {
            out[gbase + tid] = s_part[0][tid] + s_part[1][tid]
                             + s_part[2][tid] + s_part[3][tid] + bias2;
        }
    };

    A(0);
    __syncthreads();
#pragma unroll 1
    for (int ch = 0; ch < 4; ++ch) {
        Bp(ch);
        __syncthreads();
        Cp();
        __syncthreads();
        Dp(ch);                      // reads s_part
        if (ch < 3) A(ch + 1);       // writes s_mc/s_te1 — disjoint, overlapped
        __syncthreads();
    }
}

extern "C" void kernel_launch(void* const* d_in, const int* in_sizes, int n_in,
                              void* d_out, int out_size, void* d_ws, size_t ws_size,
                              hipStream_t stream)
{
    const float* x     = (const float*)d_in[0];
    const float* t     = (const float*)d_in[1];
    const float* mtok  = (const float*)d_in[2];
    const float* te_w1 = (const float*)d_in[3];
    const float* te_b1 = (const float*)d_in[4];
    const float* te_w2 = (const float*)d_in[5];
    const float* te_b2 = (const float*)d_in[6];
    const float* fpw   = (const float*)d_in[7];
    const float* fpb   = (const float*)d_in[8];
    const float* bpw   = (const float*)d_in[9];
    const float* bpb   = (const float*)d_in[10];
    const float* fwz   = (const float*)d_in[11];
    const float* fbz   = (const float*)d_in[12];
    const float* fwh   = (const float*)d_in[13];
    const float* fbh   = (const float*)d_in[14];
    const float* bwz   = (const float*)d_in[15];
    const float* bbz   = (const float*)d_in[16];
    const float* bwh   = (const float*)d_in[17];
    const float* bbh   = (const float*)d_in[18];
    const float* w1    = (const float*)d_in[19];
    const float* b1    = (const float*)d_in[20];
    const float* w2    = (const float*)d_in[21];
    const float* b2    = (const float*)d_in[22];

    const size_t per_b = 1572864ull;
    int Bg = NB;
    while ((size_t)Bg * per_b > ws_size && Bg > 1) Bg >>= 1;
    const int nG = NB / Bg;

    char* ws = (char*)d_ws;
    uint32_t*       abf  = (uint32_t*)(ws);
    uint32_t*       abb  = abf + (size_t)Bg * 64 * NL;
    unsigned short* hf   = (unsigned short*)(abb + (size_t)Bg * 64 * NL);
    unsigned short* hb   = hf + (size_t)Bg * NL * 64;

    for (int g = 0; g < nG; ++g) {
        const int b0 = g * Bg;

        prep_kernel<<<8 * Bg, 256, 0, stream>>>(
            x, t, mtok, te_w1, te_b1, te_w2, te_b2,
            fpw, fpb, bpw, bpb, fwz, fbz, fwh, fbh, bwz, bbz, bwh, bbh,
            b0, abf, abb);

        scan3_kernel<<<4 * Bg, 256, 0, stream>>>(abf, abb, hf, hb);

        head_kernel<<<8 * Bg, 256, 0, stream>>>(
            x, t, te_w1, te_b1, te_w2, te_b2,
            hf, hb, w1, b1, w2, b2, b0, (float*)d_out);
    }
}